// Round 2
// baseline (1699.889 us; speedup 1.0000x reference)
//
#include <hip/hip_runtime.h>

#define N_PTS   65536
#define LATENT  128
#define HIDDEN  512
#define OUT_D   64
#define NBUCKET 1024
#define ROWS_A  32

// ---------------- kernel A: fused MLP -> x, xnorm, bucket ----------------
// block: 32 rows. GEMM1 register tile 8 rows x 4 cols (per 256-col half),
// GEMM2 register tile 4 rows x 2 cols, acc carried across halves.
__global__ __launch_bounds__(256, 3) void mlp_kernel(
    const float* __restrict__ z, const float* __restrict__ W1,
    const float* __restrict__ b1, const float* __restrict__ W2,
    const float* __restrict__ b2, const float* __restrict__ a,
    const float* __restrict__ lsh_b,
    float* __restrict__ x_out, float* __restrict__ xnorm_out,
    int* __restrict__ bucket_out)
{
    __shared__ float zt[ROWS_A][LATENT];   // 16 KB
    __shared__ float ht[ROWS_A][256];      // 32 KB (one hidden half)
    const int t = threadIdx.x;
    const int row0 = blockIdx.x * ROWS_A;

    // load z tile (32x128 = 1024 float4), coalesced
    {
        const float4* z4 = reinterpret_cast<const float4*>(z + (size_t)row0 * LATENT);
        float4* zt4 = reinterpret_cast<float4*>(&zt[0][0]);
#pragma unroll
        for (int i = 0; i < 4; ++i) zt4[t + 256 * i] = z4[t + 256 * i];
    }
    __syncthreads();

    const int tx = t & 63, ty = t >> 6;     // GEMM1: rows ty*8..+7, cols tx+64c
    const int txq = t & 31, tyq = t >> 5;   // GEMM2: rows tyq*4..+3, cols txq, txq+32

    float acc2[4][2];
#pragma unroll
    for (int i = 0; i < 4; ++i) { acc2[i][0] = 0.f; acc2[i][1] = 0.f; }

    for (int h = 0; h < 2; ++h) {
        // ---- GEMM1 half: h_cols [h*256, h*256+256) ----
        float acc1[8][4];
#pragma unroll
        for (int i = 0; i < 8; ++i)
#pragma unroll
            for (int c = 0; c < 4; ++c) acc1[i][c] = 0.f;

        const int jbase = h * 256 + tx;
#pragma unroll 2
        for (int k = 0; k < LATENT; k += 4) {
            float w[4][4];
#pragma unroll
            for (int kk = 0; kk < 4; ++kk)
#pragma unroll
                for (int c = 0; c < 4; ++c)
                    w[kk][c] = W1[(size_t)(k + kk) * HIDDEN + jbase + 64 * c];
            float4 zv[8];
#pragma unroll
            for (int i = 0; i < 8; ++i)
                zv[i] = *reinterpret_cast<const float4*>(&zt[ty * 8 + i][k]);
#pragma unroll
            for (int i = 0; i < 8; ++i)
#pragma unroll
                for (int c = 0; c < 4; ++c) {
                    acc1[i][c] = fmaf(zv[i].x, w[0][c], acc1[i][c]);
                    acc1[i][c] = fmaf(zv[i].y, w[1][c], acc1[i][c]);
                    acc1[i][c] = fmaf(zv[i].z, w[2][c], acc1[i][c]);
                    acc1[i][c] = fmaf(zv[i].w, w[3][c], acc1[i][c]);
                }
        }
        // bias + relu -> ht
        float bb[4];
#pragma unroll
        for (int c = 0; c < 4; ++c) bb[c] = b1[jbase + 64 * c];
#pragma unroll
        for (int i = 0; i < 8; ++i)
#pragma unroll
            for (int c = 0; c < 4; ++c)
                ht[ty * 8 + i][tx + 64 * c] = fmaxf(acc1[i][c] + bb[c], 0.f);
        __syncthreads();

        // ---- GEMM2 partial over this half's k range ----
#pragma unroll 2
        for (int k = 0; k < 256; k += 4) {
            float w2[4][2];
#pragma unroll
            for (int kk = 0; kk < 4; ++kk) {
                w2[kk][0] = W2[(size_t)(h * 256 + k + kk) * OUT_D + txq];
                w2[kk][1] = W2[(size_t)(h * 256 + k + kk) * OUT_D + txq + 32];
            }
            float4 hv[4];
#pragma unroll
            for (int i = 0; i < 4; ++i)
                hv[i] = *reinterpret_cast<const float4*>(&ht[tyq * 4 + i][k]);
#pragma unroll
            for (int i = 0; i < 4; ++i)
#pragma unroll
                for (int c = 0; c < 2; ++c) {
                    acc2[i][c] = fmaf(hv[i].x, w2[0][c], acc2[i][c]);
                    acc2[i][c] = fmaf(hv[i].y, w2[1][c], acc2[i][c]);
                    acc2[i][c] = fmaf(hv[i].z, w2[2][c], acc2[i][c]);
                    acc2[i][c] = fmaf(hv[i].w, w2[3][c], acc2[i][c]);
                }
        }
        __syncthreads();
    }

    // ---- epilogue: bias, store x, per-row LSH bucket + ||x||^2 ----
    const float bb0 = b2[txq], bb1 = b2[txq + 32];
    const float a0 = a[txq], a1 = a[txq + 32];
    const float lb = lsh_b[0];
    float xv0[4], xv1[4];
#pragma unroll
    for (int i = 0; i < 4; ++i) {
        xv0[i] = acc2[i][0] + bb0;
        xv1[i] = acc2[i][1] + bb1;
        const int row = row0 + tyq * 4 + i;
        x_out[(size_t)row * OUT_D + txq] = xv0[i];
        x_out[(size_t)row * OUT_D + txq + 32] = xv1[i];
    }
#pragma unroll
    for (int i = 0; i < 4; ++i) {
        float sa = fmaf(xv0[i], a0, xv1[i] * a1);
        float sn = fmaf(xv0[i], xv0[i], xv1[i] * xv1[i]);
#pragma unroll
        for (int off = 16; off >= 1; off >>= 1) {
            sa += __shfl_xor(sa, off, 32);
            sn += __shfl_xor(sn, off, 32);
        }
        if (txq == 0) {
            const int row = row0 + tyq * 4 + i;
            const float code = floorf((sa + lb) * 0.25f);
            bucket_out[row] = ((int)code) & (NBUCKET - 1);
            xnorm_out[row] = sn;
        }
    }
}

// ---------------- kernel B: segment means via bucket-scan (no atomics) ----------------
// one block per bucket; 4 waves scan quarters of the id array, accumulate in regs.
__global__ __launch_bounds__(256) void seg_mean_kernel(
    const float* __restrict__ x, const int* __restrict__ bucket,
    float* __restrict__ means_out, float* __restrict__ mnorm)
{
    __shared__ float partial[4][64];
    __shared__ int pcnt[4];
    const int b = blockIdx.x;
    const int t = threadIdx.x;
    const int lane = t & 63, w = t >> 6;
    const int base = w * (N_PTS / 4);
    float s = 0.f;
    int cnt = 0;
    for (int it = 0; it < (N_PTS / 4) / 64; ++it) {
        const int rbase = base + it * 64;
        const int bk = bucket[rbase + lane];
        unsigned long long m = __ballot(bk == b);
        cnt += (int)__popcll(m);
        while (m) {
            const int src = __builtin_ctzll(m);
            m &= (m - 1);
            s += x[(size_t)(rbase + src) * OUT_D + lane];
        }
    }
    partial[w][lane] = s;
    if (lane == 0) pcnt[w] = cnt;
    __syncthreads();
    if (w == 0) {
        const float tot = partial[0][lane] + partial[1][lane] + partial[2][lane] + partial[3][lane];
        const float c = fmaxf((float)(pcnt[0] + pcnt[1] + pcnt[2] + pcnt[3]), 1.0f);
        const float mval = tot / c;
        means_out[(size_t)b * OUT_D + lane] = mval;
        float s2 = mval * mval;
#pragma unroll
        for (int off = 32; off >= 1; off >>= 1) s2 += __shfl_xor(s2, off, 64);
        if (lane == 0) mnorm[b] = s2;
    }
}

// ---------------- kernel C: q_s via gram trick (unchanged from r1) ----------------
__global__ __launch_bounds__(256) void q_kernel(
    const float* __restrict__ x, const float* __restrict__ xnorm,
    const float* __restrict__ means, const float* __restrict__ mnorm,
    float* __restrict__ q_out)
{
    __shared__ float4 mlds4[256 * 16];  // 64 KB
    __shared__ float4 xlds4[16 * 16];   // 4 KB
    const int t = threadIdx.x;
    const int l = t & 63;
    const int w = t >> 6;
    const int row0 = blockIdx.x * 16;
    const float4* x4 = reinterpret_cast<const float4*>(x);
    const float4* m4 = reinterpret_cast<const float4*>(means);

    xlds4[t] = x4[(size_t)row0 * 16 + t];

    float xn[4];
#pragma unroll
    for (int r = 0; r < 4; ++r) xn[r] = xnorm[row0 + w * 4 + r];

    float q[4][4][4];
    float rs[4] = {0.f, 0.f, 0.f, 0.f};
    const int sl = l & 7;

#pragma unroll
    for (int cb = 0; cb < 4; ++cb) {
        __syncthreads();
        for (int i = t; i < 256 * 16; i += 256) {
            const int b = i >> 4, k4 = i & 15;
            mlds4[b * 16 + (k4 ^ (b & 7))] = m4[(size_t)(cb * 256 + b) * 16 + k4];
        }
        __syncthreads();

        float acc[4][4];
#pragma unroll
        for (int r = 0; r < 4; ++r)
#pragma unroll
            for (int bb = 0; bb < 4; ++bb) acc[r][bb] = 0.f;

#pragma unroll 4
        for (int k4 = 0; k4 < 16; ++k4) {
            float4 xv[4];
#pragma unroll
            for (int r = 0; r < 4; ++r) xv[r] = xlds4[(w * 4 + r) * 16 + k4];
            float4 mv[4];
#pragma unroll
            for (int bb = 0; bb < 4; ++bb)
                mv[bb] = mlds4[(bb * 64 + l) * 16 + (k4 ^ sl)];
#pragma unroll
            for (int r = 0; r < 4; ++r)
#pragma unroll
                for (int bb = 0; bb < 4; ++bb) {
                    acc[r][bb] = fmaf(xv[r].x, mv[bb].x, acc[r][bb]);
                    acc[r][bb] = fmaf(xv[r].y, mv[bb].y, acc[r][bb]);
                    acc[r][bb] = fmaf(xv[r].z, mv[bb].z, acc[r][bb]);
                    acc[r][bb] = fmaf(xv[r].w, mv[bb].w, acc[r][bb]);
                }
        }
#pragma unroll
        for (int bb = 0; bb < 4; ++bb) {
            const float mn = mnorm[cb * 256 + bb * 64 + l];
#pragma unroll
            for (int r = 0; r < 4; ++r) {
                const float d2 = fmaxf(xn[r] + mn - 2.f * acc[r][bb], 0.f);
                const float qq = 1.f / (1.f + d2);
                q[cb][r][bb] = qq;
                rs[r] += qq;
            }
        }
    }

#pragma unroll
    for (int off = 32; off >= 1; off >>= 1)
#pragma unroll
        for (int r = 0; r < 4; ++r) rs[r] += __shfl_xor(rs[r], off, 64);

    float inv[4];
#pragma unroll
    for (int r = 0; r < 4; ++r) inv[r] = 1.f / rs[r];

#pragma unroll
    for (int cb = 0; cb < 4; ++cb)
#pragma unroll
        for (int r = 0; r < 4; ++r) {
            const size_t base = (size_t)(row0 + w * 4 + r) * NBUCKET + cb * 256 + l;
#pragma unroll
            for (int bb = 0; bb < 4; ++bb)
                q_out[base + bb * 64] = q[cb][r][bb] * inv[r];
        }
}

extern "C" void kernel_launch(void* const* d_in, const int* in_sizes, int n_in,
                              void* d_out, int out_size, void* d_ws, size_t ws_size,
                              hipStream_t stream) {
    const float* z    = (const float*)d_in[0];
    const float* W1   = (const float*)d_in[1];
    const float* b1   = (const float*)d_in[2];
    const float* W2   = (const float*)d_in[3];
    const float* b2   = (const float*)d_in[4];
    const float* a    = (const float*)d_in[5];
    const float* lshb = (const float*)d_in[6];

    float* q_out     = (float*)d_out;
    float* means_out = q_out + (size_t)N_PTS * NBUCKET;   // outputs: (q_s, means)

    float* ws     = (float*)d_ws;
    float* x      = ws;                                   // N*64
    float* xnorm  = x + (size_t)N_PTS * OUT_D;            // N
    int*   bucket = (int*)(xnorm + N_PTS);                // N ints
    float* mnorm  = (float*)(bucket + N_PTS);             // B

    mlp_kernel<<<N_PTS / ROWS_A, 256, 0, stream>>>(z, W1, b1, W2, b2, a, lshb,
                                                   x, xnorm, bucket);
    seg_mean_kernel<<<NBUCKET, 256, 0, stream>>>(x, bucket, means_out, mnorm);
    q_kernel<<<N_PTS / 16, 256, 0, stream>>>(x, xnorm, means_out, mnorm, q_out);
}

// Round 3
// 958.597 us; speedup vs baseline: 1.7733x; 1.7733x over previous
//
#include <hip/hip_runtime.h>

#define N_PTS   65536
#define LATENT  128
#define HIDDEN  512
#define OUT_D   64
#define NBUCKET 1024
#define ROWS_A  32

// ---------------- kernel A: fused MLP -> x, xnorm, bucket + atomic seg sums ----------------
__global__ __launch_bounds__(256, 3) void mlp_kernel(
    const float* __restrict__ z, const float* __restrict__ W1,
    const float* __restrict__ b1, const float* __restrict__ W2,
    const float* __restrict__ b2, const float* __restrict__ a,
    const float* __restrict__ lsh_b,
    float* __restrict__ x_out, float* __restrict__ xnorm_out,
    float* __restrict__ sums, float* __restrict__ counts)
{
    __shared__ float zt[ROWS_A][LATENT];   // 16 KB
    __shared__ float ht[ROWS_A][256];      // 32 KB (one hidden half)
    const int t = threadIdx.x;
    const int row0 = blockIdx.x * ROWS_A;

    // load z tile (32x128 = 1024 float4), coalesced
    {
        const float4* z4 = reinterpret_cast<const float4*>(z + (size_t)row0 * LATENT);
        float4* zt4 = reinterpret_cast<float4*>(&zt[0][0]);
#pragma unroll
        for (int i = 0; i < 4; ++i) zt4[t + 256 * i] = z4[t + 256 * i];
    }
    __syncthreads();

    const int tx = t & 63, ty = t >> 6;     // GEMM1: rows ty*8..+7, cols tx+64c
    const int txq = t & 31, tyq = t >> 5;   // GEMM2: rows tyq*4..+3, cols txq, txq+32

    float acc2[4][2];
#pragma unroll
    for (int i = 0; i < 4; ++i) { acc2[i][0] = 0.f; acc2[i][1] = 0.f; }

    for (int h = 0; h < 2; ++h) {
        // ---- GEMM1 half: h_cols [h*256, h*256+256) ----
        float acc1[8][4];
#pragma unroll
        for (int i = 0; i < 8; ++i)
#pragma unroll
            for (int c = 0; c < 4; ++c) acc1[i][c] = 0.f;

        const int jbase = h * 256 + tx;
#pragma unroll 2
        for (int k = 0; k < LATENT; k += 4) {
            float w[4][4];
#pragma unroll
            for (int kk = 0; kk < 4; ++kk)
#pragma unroll
                for (int c = 0; c < 4; ++c)
                    w[kk][c] = W1[(size_t)(k + kk) * HIDDEN + jbase + 64 * c];
            float4 zv[8];
#pragma unroll
            for (int i = 0; i < 8; ++i)
                zv[i] = *reinterpret_cast<const float4*>(&zt[ty * 8 + i][k]);
#pragma unroll
            for (int i = 0; i < 8; ++i)
#pragma unroll
                for (int c = 0; c < 4; ++c) {
                    acc1[i][c] = fmaf(zv[i].x, w[0][c], acc1[i][c]);
                    acc1[i][c] = fmaf(zv[i].y, w[1][c], acc1[i][c]);
                    acc1[i][c] = fmaf(zv[i].z, w[2][c], acc1[i][c]);
                    acc1[i][c] = fmaf(zv[i].w, w[3][c], acc1[i][c]);
                }
        }
        // bias + relu -> ht
        float bb[4];
#pragma unroll
        for (int c = 0; c < 4; ++c) bb[c] = b1[jbase + 64 * c];
#pragma unroll
        for (int i = 0; i < 8; ++i)
#pragma unroll
            for (int c = 0; c < 4; ++c)
                ht[ty * 8 + i][tx + 64 * c] = fmaxf(acc1[i][c] + bb[c], 0.f);
        __syncthreads();

        // ---- GEMM2 partial over this half's k range ----
#pragma unroll 2
        for (int k = 0; k < 256; k += 4) {
            float w2[4][2];
#pragma unroll
            for (int kk = 0; kk < 4; ++kk) {
                w2[kk][0] = W2[(size_t)(h * 256 + k + kk) * OUT_D + txq];
                w2[kk][1] = W2[(size_t)(h * 256 + k + kk) * OUT_D + txq + 32];
            }
            float4 hv[4];
#pragma unroll
            for (int i = 0; i < 4; ++i)
                hv[i] = *reinterpret_cast<const float4*>(&ht[tyq * 4 + i][k]);
#pragma unroll
            for (int i = 0; i < 4; ++i)
#pragma unroll
                for (int c = 0; c < 2; ++c) {
                    acc2[i][c] = fmaf(hv[i].x, w2[0][c], acc2[i][c]);
                    acc2[i][c] = fmaf(hv[i].y, w2[1][c], acc2[i][c]);
                    acc2[i][c] = fmaf(hv[i].z, w2[2][c], acc2[i][c]);
                    acc2[i][c] = fmaf(hv[i].w, w2[3][c], acc2[i][c]);
                }
        }
        __syncthreads();
    }

    // ---- epilogue: bias, store x, per-row LSH bucket + ||x||^2 + atomic seg sums ----
    const float bb0 = b2[txq], bb1 = b2[txq + 32];
    const float a0 = a[txq], a1 = a[txq + 32];
    const float lb = lsh_b[0];
#pragma unroll
    for (int i = 0; i < 4; ++i) {
        const int row = row0 + tyq * 4 + i;
        const float x0 = acc2[i][0] + bb0;
        const float x1 = acc2[i][1] + bb1;
        x_out[(size_t)row * OUT_D + txq] = x0;
        x_out[(size_t)row * OUT_D + txq + 32] = x1;

        float sa = fmaf(x0, a0, x1 * a1);
        float sn = fmaf(x0, x0, x1 * x1);
#pragma unroll
        for (int off = 16; off >= 1; off >>= 1) {
            sa += __shfl_xor(sa, off, 32);
            sn += __shfl_xor(sn, off, 32);
        }
        // all 32 lanes of the row-group now hold sa/sn
        const float code = floorf((sa + lb) * 0.25f);   // /4.0 exact
        const int bkt = ((int)code) & (NBUCKET - 1);    // python-mod, pow2
        if (txq == 0) {
            xnorm_out[row] = sn;
            atomicAdd(&counts[bkt], 1.0f);
        }
        atomicAdd(&sums[(size_t)bkt * OUT_D + txq], x0);
        atomicAdd(&sums[(size_t)bkt * OUT_D + txq + 32], x1);
    }
}

// ---------------- kernel B: means = sums / max(counts,1); mnorm ----------------
__global__ __launch_bounds__(64) void means_kernel(
    const float* __restrict__ sums, const float* __restrict__ counts,
    float* __restrict__ means_out, float* __restrict__ mnorm)
{
    const int b = blockIdx.x;
    const int k = threadIdx.x;
    const float c = fmaxf(counts[b], 1.0f);
    const float m = sums[b * 64 + k] / c;
    means_out[b * 64 + k] = m;
    float s = m * m;
#pragma unroll
    for (int off = 32; off >= 1; off >>= 1) s += __shfl_xor(s, off, 64);
    if (k == 0) mnorm[b] = s;
}

// ---------------- kernel C: q_s via gram trick ----------------
__global__ __launch_bounds__(256) void q_kernel(
    const float* __restrict__ x, const float* __restrict__ xnorm,
    const float* __restrict__ means, const float* __restrict__ mnorm,
    float* __restrict__ q_out)
{
    __shared__ float4 mlds4[256 * 16];  // 64 KB
    __shared__ float4 xlds4[16 * 16];   // 4 KB
    const int t = threadIdx.x;
    const int l = t & 63;
    const int w = t >> 6;
    const int row0 = blockIdx.x * 16;
    const float4* x4 = reinterpret_cast<const float4*>(x);
    const float4* m4 = reinterpret_cast<const float4*>(means);

    xlds4[t] = x4[(size_t)row0 * 16 + t];

    float xn[4];
#pragma unroll
    for (int r = 0; r < 4; ++r) xn[r] = xnorm[row0 + w * 4 + r];

    float q[4][4][4];
    float rs[4] = {0.f, 0.f, 0.f, 0.f};
    const int sl = l & 7;

#pragma unroll
    for (int cb = 0; cb < 4; ++cb) {
        __syncthreads();
        for (int i = t; i < 256 * 16; i += 256) {
            const int b = i >> 4, k4 = i & 15;
            mlds4[b * 16 + (k4 ^ (b & 7))] = m4[(size_t)(cb * 256 + b) * 16 + k4];
        }
        __syncthreads();

        float acc[4][4];
#pragma unroll
        for (int r = 0; r < 4; ++r)
#pragma unroll
            for (int bb = 0; bb < 4; ++bb) acc[r][bb] = 0.f;

#pragma unroll 4
        for (int k4 = 0; k4 < 16; ++k4) {
            float4 xv[4];
#pragma unroll
            for (int r = 0; r < 4; ++r) xv[r] = xlds4[(w * 4 + r) * 16 + k4];
            float4 mv[4];
#pragma unroll
            for (int bb = 0; bb < 4; ++bb)
                mv[bb] = mlds4[(bb * 64 + l) * 16 + (k4 ^ sl)];
#pragma unroll
            for (int r = 0; r < 4; ++r)
#pragma unroll
                for (int bb = 0; bb < 4; ++bb) {
                    acc[r][bb] = fmaf(xv[r].x, mv[bb].x, acc[r][bb]);
                    acc[r][bb] = fmaf(xv[r].y, mv[bb].y, acc[r][bb]);
                    acc[r][bb] = fmaf(xv[r].z, mv[bb].z, acc[r][bb]);
                    acc[r][bb] = fmaf(xv[r].w, mv[bb].w, acc[r][bb]);
                }
        }
#pragma unroll
        for (int bb = 0; bb < 4; ++bb) {
            const float mn = mnorm[cb * 256 + bb * 64 + l];
#pragma unroll
            for (int r = 0; r < 4; ++r) {
                const float d2 = fmaxf(xn[r] + mn - 2.f * acc[r][bb], 0.f);
                const float qq = 1.f / (1.f + d2);
                q[cb][r][bb] = qq;
                rs[r] += qq;
            }
        }
    }

#pragma unroll
    for (int off = 32; off >= 1; off >>= 1)
#pragma unroll
        for (int r = 0; r < 4; ++r) rs[r] += __shfl_xor(rs[r], off, 64);

    float inv[4];
#pragma unroll
    for (int r = 0; r < 4; ++r) inv[r] = 1.f / rs[r];

#pragma unroll
    for (int cb = 0; cb < 4; ++cb)
#pragma unroll
        for (int r = 0; r < 4; ++r) {
            const size_t base = (size_t)(row0 + w * 4 + r) * NBUCKET + cb * 256 + l;
#pragma unroll
            for (int bb = 0; bb < 4; ++bb)
                q_out[base + bb * 64] = q[cb][r][bb] * inv[r];
        }
}

extern "C" void kernel_launch(void* const* d_in, const int* in_sizes, int n_in,
                              void* d_out, int out_size, void* d_ws, size_t ws_size,
                              hipStream_t stream) {
    const float* z    = (const float*)d_in[0];
    const float* W1   = (const float*)d_in[1];
    const float* b1   = (const float*)d_in[2];
    const float* W2   = (const float*)d_in[3];
    const float* b2   = (const float*)d_in[4];
    const float* a    = (const float*)d_in[5];
    const float* lshb = (const float*)d_in[6];

    float* q_out     = (float*)d_out;
    float* means_out = q_out + (size_t)N_PTS * NBUCKET;   // outputs: (q_s, means)

    float* ws     = (float*)d_ws;
    float* x      = ws;                                   // N*64
    float* xnorm  = x + (size_t)N_PTS * OUT_D;            // N
    float* sums   = xnorm + N_PTS;                        // B*64
    float* counts = sums + (size_t)NBUCKET * OUT_D;       // B
    float* mnorm  = counts + NBUCKET;                     // B

    hipMemsetAsync(sums, 0, (size_t)(NBUCKET * OUT_D + NBUCKET) * sizeof(float), stream);

    mlp_kernel<<<N_PTS / ROWS_A, 256, 0, stream>>>(z, W1, b1, W2, b2, a, lshb,
                                                   x, xnorm, sums, counts);
    means_kernel<<<NBUCKET, 64, 0, stream>>>(sums, counts, means_out, mnorm);
    q_kernel<<<N_PTS / 16, 256, 0, stream>>>(x, xnorm, means_out, mnorm, q_out);
}